// Round 1
// baseline (2512.849 us; speedup 1.0000x reference)
//
#include <hip/hip_runtime.h>
#include <math.h>

// Problem constants
#define B_  1
#define L_  4096
#define D_  2048
#define H_  8
#define KVH_ 2
#define HD_ 256
#define WINDOW_ 512

// ---------------------------------------------------------------------------
// fp32 tiled GEMM: C[M,N] = A[M,K] @ B[K,N], all row-major, dims % 64 == 0
// 64x64 block tile, 16-wide K-step, 256 threads, 4x4 micro-tile per thread.
// ---------------------------------------------------------------------------
__global__ __launch_bounds__(256) void gemm_f32(const float* __restrict__ A,
                                                const float* __restrict__ Bm,
                                                float* __restrict__ C,
                                                int M, int N, int K) {
    __shared__ float As[16][68];   // [k][m], padded row (68*4B = 16B-aligned rows)
    __shared__ float Bs[16][64];   // [k][n]

    const int tid = threadIdx.x;
    const int tx = tid & 15;       // n-direction
    const int ty = tid >> 4;       // m-direction
    const int bm = blockIdx.y * 64;
    const int bn = blockIdx.x * 64;

    float acc[4][4] = {};

    for (int k0 = 0; k0 < K; k0 += 16) {
        // Stage A tile (64 rows x 16 k): one float4 per thread
        {
            int m  = tid >> 2;
            int kq = (tid & 3) << 2;
            const float4 av = *(const float4*)(A + (size_t)(bm + m) * K + k0 + kq);
            As[kq + 0][m] = av.x;
            As[kq + 1][m] = av.y;
            As[kq + 2][m] = av.z;
            As[kq + 3][m] = av.w;
        }
        // Stage B tile (16 k-rows x 64 n): one float4 per thread, coalesced
        {
            int kk = tid >> 4;
            int nn = (tid & 15) << 2;
            const float4 bv = *(const float4*)(Bm + (size_t)(k0 + kk) * N + bn + nn);
            *(float4*)&Bs[kk][nn] = bv;
        }
        __syncthreads();

#pragma unroll
        for (int kk = 0; kk < 16; ++kk) {
            float4 av = *(const float4*)&As[kk][ty * 4];
            float4 bv = *(const float4*)&Bs[kk][tx * 4];
            float a[4] = {av.x, av.y, av.z, av.w};
            float b[4] = {bv.x, bv.y, bv.z, bv.w};
#pragma unroll
            for (int i = 0; i < 4; ++i)
#pragma unroll
                for (int j = 0; j < 4; ++j)
                    acc[i][j] += a[i] * b[j];
        }
        __syncthreads();
    }

#pragma unroll
    for (int i = 0; i < 4; ++i) {
        float4 cv = make_float4(acc[i][0], acc[i][1], acc[i][2], acc[i][3]);
        *(float4*)(C + (size_t)(bm + ty * 4 + i) * N + bn + tx * 4) = cv;
    }
}

// ---------------------------------------------------------------------------
// Fused RMSNorm (+ optional scale) (+ optional full-head RoPE), in place.
// One block of 256 threads per (token, head) row of HD_=256 elements.
// buf layout: [L, nheads*HD_] with heads contiguous -> row = token*nheads + h
// ---------------------------------------------------------------------------
__global__ __launch_bounds__(256) void norm_rope(float* __restrict__ buf,
                                                 const float* __restrict__ scale,
                                                 const int* __restrict__ positions,
                                                 int nheads, int do_rope) {
    const int row = blockIdx.x;
    const int qi  = row / nheads;
    float* p = buf + (size_t)row * HD_;
    const int d = threadIdx.x;

    float val = p[d];

    // block-reduce sum of squares (4 waves)
    float ss = val * val;
#pragma unroll
    for (int off = 32; off > 0; off >>= 1) ss += __shfl_down(ss, off);
    __shared__ float wss[4];
    __shared__ float xs[HD_];
    if ((d & 63) == 0) wss[d >> 6] = ss;
    __syncthreads();
    const float var = (wss[0] + wss[1] + wss[2] + wss[3]) * (1.0f / (float)HD_);
    float xn = val * rsqrtf(var + 1e-6f);
    if (scale) xn *= scale[d];

    if (!do_rope) {
        p[d] = xn;
        return;
    }

    xs[d] = xn;
    __syncthreads();

    const int   pos = positions[qi];
    const int   i   = d & 127;                       // pair index within half
    const float fe  = (float)(2 * i) / (float)HD_;   // 2i/256
    const float ts  = powf(10000.0f, fe);
    const float ang = (float)pos / ts;
    float s, c;
    __sincosf(ang, &s, &c);

    float out;
    if (d < 128) out = xn * c - xs[d + 128] * s;   // x1r = x1*cos - x2*sin
    else         out = xn * c + xs[d - 128] * s;   // x2r = x2*cos + x1*sin
    p[d] = out;
}

// ---------------------------------------------------------------------------
// Sliding-window attention, one block (512 threads) per query token.
// Computes all 8 heads: scores (each thread = one key slot), wave-per-head
// softmax, then PV with coalesced V reads (thread = (kv-group, dim)).
// q: [L, H_*HD_]  k,v: [L, KVH_*HD_]  out: [L, H_*HD_]
// ---------------------------------------------------------------------------
__global__ __launch_bounds__(512) void attn_kernel(const float* __restrict__ q,
                                                   const float* __restrict__ k,
                                                   const float* __restrict__ v,
                                                   float* __restrict__ out) {
    const int qi  = blockIdx.x;
    const int tid = threadIdx.x;

    __shared__ float qs[H_][HD_];       // 8 KB
    __shared__ float sc[H_][WINDOW_];   // 16 KB (scores -> exp weights)
    __shared__ float invs[H_];

    // load this token's 8 q-head rows
    for (int i = tid; i < H_ * HD_; i += 512)
        qs[i >> 8][i & 255] = q[(size_t)qi * (H_ * HD_) + i];
    __syncthreads();

    // ---- scores: thread j handles key kj = qi - 511 + j ----
    const int j  = tid;
    const int kj = qi - (WINDOW_ - 1) + j;
    float acc[H_];
#pragma unroll
    for (int h = 0; h < H_; ++h) acc[h] = 0.0f;

    if (kj >= 0) {
        const float4* k0 = (const float4*)(k + (size_t)kj * (KVH_ * HD_));          // kvh 0
        const float4* k1 = k0 + (HD_ / 4);                                          // kvh 1
#pragma unroll 4
        for (int d4 = 0; d4 < HD_ / 4; ++d4) {
            float4 a = k0[d4];
            float4 b = k1[d4];
            const int d = d4 * 4;
#pragma unroll
            for (int h = 0; h < 4; ++h) {
                acc[h] += qs[h][d + 0] * a.x + qs[h][d + 1] * a.y +
                          qs[h][d + 2] * a.z + qs[h][d + 3] * a.w;
            }
#pragma unroll
            for (int h = 4; h < 8; ++h) {
                acc[h] += qs[h][d + 0] * b.x + qs[h][d + 1] * b.y +
                          qs[h][d + 2] * b.z + qs[h][d + 3] * b.w;
            }
        }
    }
#pragma unroll
    for (int h = 0; h < H_; ++h)
        sc[h][j] = (kj >= 0) ? acc[h] : -INFINITY;
    __syncthreads();

    // ---- softmax: wave w handles head w ----
    {
        const int h    = tid >> 6;
        const int lane = tid & 63;
        float m = -INFINITY;
        for (int i = lane; i < WINDOW_; i += 64) m = fmaxf(m, sc[h][i]);
#pragma unroll
        for (int off = 32; off > 0; off >>= 1) m = fmaxf(m, __shfl_down(m, off));
        m = __shfl(m, 0);
        float ssum = 0.0f;
        for (int i = lane; i < WINDOW_; i += 64) {
            float e = expf(sc[h][i] - m);   // exp(-inf)=0 handles masked slots
            sc[h][i] = e;
            ssum += e;
        }
#pragma unroll
        for (int off = 32; off > 0; off >>= 1) ssum += __shfl_down(ssum, off);
        if (lane == 0) invs[h] = 1.0f / ssum;
    }
    __syncthreads();

    // ---- PV: thread = (g, d); g in {0,1} selects kv head + 4 q-heads ----
    {
        const int d = tid & 255;
        const int g = tid >> 8;
        float o0 = 0.f, o1 = 0.f, o2 = 0.f, o3 = 0.f;
        const int j0 = (qi >= WINDOW_ - 1) ? 0 : (WINDOW_ - 1 - qi);
        const float* vbase = v + (size_t)g * HD_ + d;
        for (int jj = j0; jj < WINDOW_; ++jj) {
            const int kk = qi - (WINDOW_ - 1) + jj;
            const float vv = vbase[(size_t)kk * (KVH_ * HD_)];
            o0 += sc[g * 4 + 0][jj] * vv;
            o1 += sc[g * 4 + 1][jj] * vv;
            o2 += sc[g * 4 + 2][jj] * vv;
            o3 += sc[g * 4 + 3][jj] * vv;
        }
        float* obase = out + (size_t)qi * (H_ * HD_) + (size_t)g * 4 * HD_ + d;
        obase[0 * HD_] = o0 * invs[g * 4 + 0];
        obase[1 * HD_] = o1 * invs[g * 4 + 1];
        obase[2 * HD_] = o2 * invs[g * 4 + 2];
        obase[3 * HD_] = o3 * invs[g * 4 + 3];
    }
}

// ---------------------------------------------------------------------------
extern "C" void kernel_launch(void* const* d_in, const int* in_sizes, int n_in,
                              void* d_out, int out_size, void* d_ws, size_t ws_size,
                              hipStream_t stream) {
    const float* x         = (const float*)d_in[0];
    const int*   positions = (const int*)d_in[1];
    const float* Wq        = (const float*)d_in[2];
    const float* Wk        = (const float*)d_in[3];
    const float* Wv        = (const float*)d_in[4];
    const float* Wo        = (const float*)d_in[5];
    const float* q_scale   = (const float*)d_in[6];
    const float* k_scale   = (const float*)d_in[7];
    float*       out       = (float*)d_out;

    // workspace layout (floats)
    float* q    = (float*)d_ws;                       // 4096*2048
    float* kbuf = q    + (size_t)L_ * H_ * HD_;       // 4096*512
    float* vbuf = kbuf + (size_t)L_ * KVH_ * HD_;     // 4096*512
    float* attn = vbuf + (size_t)L_ * KVH_ * HD_;     // 4096*2048

    // 1) QKV projections
    gemm_f32<<<dim3((H_ * HD_) / 64, L_ / 64), 256, 0, stream>>>(x, Wq, q,    L_, H_ * HD_,   D_);
    gemm_f32<<<dim3((KVH_ * HD_) / 64, L_ / 64), 256, 0, stream>>>(x, Wk, kbuf, L_, KVH_ * HD_, D_);
    gemm_f32<<<dim3((KVH_ * HD_) / 64, L_ / 64), 256, 0, stream>>>(x, Wv, vbuf, L_, KVH_ * HD_, D_);

    // 2) RMSNorm (+ scale) + RoPE
    norm_rope<<<L_ * H_,   256, 0, stream>>>(q,    q_scale, positions, H_,   1);
    norm_rope<<<L_ * KVH_, 256, 0, stream>>>(kbuf, k_scale, positions, KVH_, 1);
    norm_rope<<<L_ * KVH_, 256, 0, stream>>>(vbuf, nullptr, positions, KVH_, 0);

    // 3) sliding-window attention
    attn_kernel<<<L_, 512, 0, stream>>>(q, kbuf, vbuf, attn);

    // 4) output projection
    gemm_f32<<<dim3(D_ / 64, L_ / 64), 256, 0, stream>>>(attn, Wo, out, L_, D_, D_);
}

// Round 3
// 401.241 us; speedup vs baseline: 6.2627x; 6.2627x over previous
//
#include <hip/hip_runtime.h>
#include <hip/hip_bf16.h>
#include <math.h>
#include <stdint.h>

#define L_      4096
#define D_      2048
#define H_      8
#define KVH_    2
#define HD_     256
#define WINDOW_ 512
#define QKVW    3072   // 2048 q + 512 k + 512 v

typedef __attribute__((ext_vector_type(8))) _Float16 f16x8;
typedef __attribute__((ext_vector_type(4))) short s16x4;
typedef __attribute__((ext_vector_type(4))) float f32x4;

__device__ __forceinline__ short f2h(float f) {
    _Float16 h = (_Float16)f;           // RNE
    return *reinterpret_cast<short*>(&h);
}
__device__ __forceinline__ float h2f(short s) {
    _Float16 h = *reinterpret_cast<_Float16*>(&s);
    return (float)h;
}

// async global->LDS 16B per lane; lds base must be wave-uniform
__device__ __forceinline__ void gl2lds16(const void* g, void* l) {
    __builtin_amdgcn_global_load_lds(
        (const __attribute__((address_space(1))) uint32_t*)g,
        (__attribute__((address_space(3))) uint32_t*)l, 16, 0, 0);
}

// ---------------------------------------------------------------------------
// cast fp32 -> fp16 (bits in short), 8 elems/thread
// ---------------------------------------------------------------------------
__global__ __launch_bounds__(256) void cast_f16(const float* __restrict__ X,
                                                short* __restrict__ Y, int n) {
    int idx = (blockIdx.x * 256 + threadIdx.x) * 8;
    if (idx >= n) return;
    float4 a = *(const float4*)(X + idx);
    float4 b = *(const float4*)(X + idx + 4);
    s16x4 o0, o1;
    o0[0]=f2h(a.x); o0[1]=f2h(a.y); o0[2]=f2h(a.z); o0[3]=f2h(a.w);
    o1[0]=f2h(b.x); o1[1]=f2h(b.y); o1[2]=f2h(b.z); o1[3]=f2h(b.w);
    *(s16x4*)(Y + idx)     = o0;
    *(s16x4*)(Y + idx + 4) = o1;
}

// ---------------------------------------------------------------------------
// transpose-cast: W fp32 [K][N] -> Wt fp16 [N][K]
// ---------------------------------------------------------------------------
__global__ __launch_bounds__(256) void transpose_cast(const float* __restrict__ W,
                                                      short* __restrict__ Wt,
                                                      int K, int N) {
    __shared__ float tl[32][33];
    int t = threadIdx.x;
    int c = t & 31, r4 = (t >> 5) * 4;
    int k0 = blockIdx.y * 32, n0 = blockIdx.x * 32;
#pragma unroll
    for (int i = 0; i < 4; ++i)
        tl[r4 + i][c] = W[(size_t)(k0 + r4 + i) * N + n0 + c];
    __syncthreads();
#pragma unroll
    for (int i = 0; i < 4; ++i)
        Wt[(size_t)(n0 + r4 + i) * K + k0 + c] = f2h(tl[c][r4 + i]);
}

// ---------------------------------------------------------------------------
// fp16 MFMA GEMM (m97 structure): C[M][N] = A[M][K] * Bt[N][K]^T
// 128x128 tile, BK=32, 256 threads (4 waves 2x2), 4x4 16x16 tiles per wave.
// ---------------------------------------------------------------------------
template <int OUT_HALF>
__global__ __launch_bounds__(256) void gemm_mfma(const short* __restrict__ A,
                                                 const short* __restrict__ Bt,
                                                 void* __restrict__ Cout,
                                                 int M, int N, int K) {
    __shared__ short As[128][32];   // 8 KB, rows 64B -> conflict-free b128 frags
    __shared__ short Bs[128][32];

    const int tid = threadIdx.x;
    const int w = tid >> 6, lane = tid & 63;
    const int lq = lane & 15, quad = lane >> 4;
    const int bm = blockIdx.y * 128, bn = blockIdx.x * 128;
    const int wm = (w & 1) * 64, wn = (w >> 1) * 64;
    const int gr = lane >> 2;        // staging: row within 16-row group
    const int gc = (lane & 3) * 8;   // staging: element offset (16B chunk)

    f32x4 acc[4][4];
#pragma unroll
    for (int i = 0; i < 4; ++i)
#pragma unroll
        for (int j = 0; j < 4; ++j) acc[i][j] = 0;

    for (int k0 = 0; k0 < K; k0 += 32) {
#pragma unroll
        for (int c = 0; c < 2; ++c) {
            int r0 = c * 64 + w * 16;   // wave-uniform
            gl2lds16(A  + (size_t)(bm + r0 + gr) * K + k0 + gc, &As[r0][0]);
            gl2lds16(Bt + (size_t)(bn + r0 + gr) * K + k0 + gc, &Bs[r0][0]);
        }
        __syncthreads();   // drains vmcnt -> staged data visible

        f16x8 af[4], bfr[4];
#pragma unroll
        for (int i = 0; i < 4; ++i) af[i]  = *(const f16x8*)&As[wm + i * 16 + lq][quad * 8];
#pragma unroll
        for (int j = 0; j < 4; ++j) bfr[j] = *(const f16x8*)&Bs[wn + j * 16 + lq][quad * 8];
#pragma unroll
        for (int i = 0; i < 4; ++i)
#pragma unroll
            for (int j = 0; j < 4; ++j)
                acc[i][j] = __builtin_amdgcn_mfma_f32_16x16x32_f16(af[i], bfr[j], acc[i][j], 0, 0, 0);
        __syncthreads();
    }

    // epilogue: C/D layout col=lane&15, row=quad*4+reg
#pragma unroll
    for (int i = 0; i < 4; ++i)
#pragma unroll
        for (int r = 0; r < 4; ++r) {
            int row = bm + wm + i * 16 + quad * 4 + r;
#pragma unroll
            for (int j = 0; j < 4; ++j) {
                int col = bn + wn + j * 16 + lq;
                float v = acc[i][j][r];
                if (OUT_HALF) ((short*)Cout)[(size_t)row * N + col] = f2h(v);
                else          ((float*)Cout)[(size_t)row * N + col] = v;
            }
        }
}

// ---------------------------------------------------------------------------
// RMSNorm (+scale) (+RoPE) in place on fp16 qkv [L][3072].
// block per (token,row): rows 0-7 = q heads, 8-9 = k heads, 10-11 = v heads
// ---------------------------------------------------------------------------
__global__ __launch_bounds__(256) void norm_rope_h(short* __restrict__ qkv,
                                                   const float* __restrict__ q_scale,
                                                   const float* __restrict__ k_scale,
                                                   const int* __restrict__ positions) {
    const int row = blockIdx.x;
    const int token = row / 12, ridx = row % 12;
    short* p = qkv + (size_t)token * QKVW + ridx * HD_;
    const int d = threadIdx.x;

    float val = h2f(p[d]);
    float ss = val * val;
#pragma unroll
    for (int off = 32; off > 0; off >>= 1) ss += __shfl_down(ss, off);
    __shared__ float wss[4];
    __shared__ float xs[HD_];
    if ((d & 63) == 0) wss[d >> 6] = ss;
    __syncthreads();
    const float var = (wss[0] + wss[1] + wss[2] + wss[3]) * (1.0f / (float)HD_);
    float xn = val * rsqrtf(var + 1e-6f);
    if (ridx < 8)       xn *= q_scale[d];
    else if (ridx < 10) xn *= k_scale[d];

    if (ridx >= 10) { p[d] = f2h(xn); return; }   // v: norm only (ridx uniform per block)

    xs[d] = xn;
    __syncthreads();
    const int pos = positions[token];
    const int i = d & 127;
    const float fe = (float)(2 * i) * (1.0f / (float)HD_);
    const float ts = powf(10000.0f, fe);
    const float ang = (float)pos / ts;
    float s, c;
    __sincosf(ang, &s, &c);
    float outv = (d < 128) ? (xn * c - xs[d + 128] * s)
                           : (xn * c + xs[d - 128] * s);
    p[d] = f2h(outv);
}

// ---------------------------------------------------------------------------
// Flash-style MFMA attention. Block = (q-tile of 32, head h), 256 threads.
// 17 K-tiles of 32 keys covering [q0-512, q0+31]. S via mfma (Q frags in
// regs), online softmax in LDS, P -> LDS (A-layout), PV with V transposed
// in LDS. Output fp16 [L][H*HD].
// ---------------------------------------------------------------------------
__global__ __launch_bounds__(256) void attn_mfma(const short* __restrict__ qkv,
                                                 short* __restrict__ ao) {
    const int bx = blockIdx.x;
    const int h = bx & 7, qt = bx >> 3;
    const int q0 = qt * 32;
    const int g = h >> 2;
    const int tid = threadIdx.x;
    const int w = tid >> 6, lane = tid & 63;
    const int lq = lane & 15, quad = lane >> 4;
    const int qh = w >> 1, jh = w & 1;
    const int qbase = qh * 16;

    __shared__ short Ks[32][264];           // rows padded +16 shorts (bank spread)
    __shared__ __align__(16) short Vt[256][40];  // V transposed, rows 80B
    __shared__ __align__(16) short pP[32][40];   // P in fp16, A-layout rows
    __shared__ float sS[32][33];
    __shared__ float mS[32], lS[32], aS[32];

    // Q fragments: A-layout, row = q0+qbase+lq, k-chunks of 8 contiguous dims
    f16x8 qf[8];
    {
        const short* qrow = qkv + (size_t)(q0 + qbase + lq) * QKVW + h * HD_;
#pragma unroll
        for (int f = 0; f < 8; ++f)
            qf[f] = *(const f16x8*)(qrow + f * 32 + quad * 8);
    }

    if (tid < 32) { mS[tid] = -INFINITY; lS[tid] = 0.0f; }

    f32x4 accO[8];
#pragma unroll
    for (int dt = 0; dt < 8; ++dt) accO[dt] = 0;

    const short* kcol = qkv + 2048 + g * HD_;
    const short* vcol = qkv + 2560 + g * HD_;

    for (int kt = 0; kt < 17; ++kt) {
        const int kbase = q0 - WINDOW_ + kt * 32;
        if (kbase + 32 <= 0) continue;   // tile fully out of range

        // --- stage K tile: thread -> (row tid>>3, 64B chunk) ---
        {
            const int row = tid >> 3;
            const int co = (tid & 7) * 32;
            int kj = kbase + row; if (kj < 0) kj = 0;   // clamped rows get masked
            const short* src = kcol + (size_t)kj * QKVW + co;
            short* dst = &Ks[row][co];
#pragma unroll
            for (int u = 0; u < 4; ++u)
                *(int4*)(dst + u * 8) = *(const int4*)(src + u * 8);
        }
        // --- stage V transposed: thread = dim d, 2 keys per iter ---
        {
#pragma unroll
            for (int jp = 0; jp < 16; ++jp) {
                int ka = kbase + 2 * jp;
                int kb = ka + 1;
                if (ka < 0) ka = 0;
                if (kb < 0) kb = 0;
                short a = vcol[(size_t)ka * QKVW + tid];
                short b = vcol[(size_t)kb * QKVW + tid];
                *(short2*)&Vt[tid][2 * jp] = make_short2(a, b);
            }
        }
        __syncthreads();

        // --- S = Q K^T: wave computes 16x16 tile [qh][jh] ---
        f32x4 sacc = 0;
#pragma unroll
        for (int f = 0; f < 8; ++f) {
            f16x8 kf = *(const f16x8*)&Ks[jh * 16 + lq][f * 32 + quad * 8];
            sacc = __builtin_amdgcn_mfma_f32_16x16x32_f16(qf[f], kf, sacc, 0, 0, 0);
        }
#pragma unroll
        for (int r = 0; r < 4; ++r)
            sS[qbase + quad * 4 + r][jh * 16 + lq] = sacc[r];
        __syncthreads();

        // --- online softmax: thread (q = tid>>3, 4 keys) ---
        {
            const int q = tid >> 3, sj = tid & 7, j0 = sj * 4;
            const int qi = q0 + q;
            float sv[4]; bool vd[4];
#pragma unroll
            for (int i = 0; i < 4; ++i) {
                int key = kbase + j0 + i;
                vd[i] = (key >= 0) && (key <= qi) && (key > qi - WINDOW_);
                sv[i] = vd[i] ? sS[q][j0 + i] : -INFINITY;
            }
            float mt = fmaxf(fmaxf(sv[0], sv[1]), fmaxf(sv[2], sv[3]));
#pragma unroll
            for (int off = 1; off < 8; off <<= 1) mt = fmaxf(mt, __shfl_xor(mt, off));
            const float m_old = mS[q];
            const float m_new = fmaxf(m_old, mt);
            float psum = 0.0f;
            s16x4 pb;
#pragma unroll
            for (int i = 0; i < 4; ++i) {
                float pv = vd[i] ? expf(sv[i] - m_new) : 0.0f;
                psum += pv;
                pb[i] = f2h(pv);
            }
#pragma unroll
            for (int off = 1; off < 8; off <<= 1) psum += __shfl_xor(psum, off);
            *(s16x4*)&pP[q][j0] = pb;   // 8B aligned (q*80 + 8*sj)
            if (sj == 0) {
                float alpha = (m_new == -INFINITY) ? 1.0f : expf(m_old - m_new);
                mS[q] = m_new;
                lS[q] = lS[q] * alpha + psum;
                aS[q] = alpha;
            }
        }
        __syncthreads();

        // --- PV: wave = (q-half qh, d-half jh), 8 d-tiles of 16 ---
        {
            float ar[4];
#pragma unroll
            for (int r = 0; r < 4; ++r) ar[r] = aS[qbase + quad * 4 + r];
            f16x8 pf = *(const f16x8*)&pP[qbase + lq][quad * 8];
#pragma unroll
            for (int dt = 0; dt < 8; ++dt) {
                f16x8 vf = *(const f16x8*)&Vt[jh * 128 + dt * 16 + lq][quad * 8];
                f32x4 t = accO[dt];
#pragma unroll
                for (int r = 0; r < 4; ++r) t[r] *= ar[r];
                accO[dt] = __builtin_amdgcn_mfma_f32_16x16x32_f16(pf, vf, t, 0, 0, 0);
            }
        }
        __syncthreads();   // protect Ks/Vt/pP before next stage
    }

    // --- write O, fp16, [token][h*256 + d] ---
#pragma unroll
    for (int dt = 0; dt < 8; ++dt)
#pragma unroll
        for (int r = 0; r < 4; ++r) {
            const int q = qbase + quad * 4 + r;
            const float inv = 1.0f / lS[q];
            const int d = jh * 128 + dt * 16 + lq;
            ao[(size_t)(q0 + q) * 2048 + h * HD_ + d] = f2h(accO[dt][r] * inv);
        }
}

// ---------------------------------------------------------------------------
extern "C" void kernel_launch(void* const* d_in, const int* in_sizes, int n_in,
                              void* d_out, int out_size, void* d_ws, size_t ws_size,
                              hipStream_t stream) {
    const float* x         = (const float*)d_in[0];
    const int*   positions = (const int*)d_in[1];
    const float* Wq        = (const float*)d_in[2];
    const float* Wk        = (const float*)d_in[3];
    const float* Wv        = (const float*)d_in[4];
    const float* Wo        = (const float*)d_in[5];
    const float* q_scale   = (const float*)d_in[6];
    const float* k_scale   = (const float*)d_in[7];
    float*       out       = (float*)d_out;

    // workspace layout (bytes, ~76 MB total)
    char* ws = (char*)d_ws;
    short* xb    = (short*)(ws);                 // [4096][2048] f16   16 MB
    short* qkv   = (short*)(ws + 16777216);      // [4096][3072] f16   24 MB
    short* ao    = (short*)(ws + 41943040);      // [4096][2048] f16   16 MB
    short* Wtqkv = (short*)(ws + 58720256);      // [3072][2048] f16   12 MB
    short* Wto   = (short*)(ws + 71303168);      // [2048][2048] f16    8 MB

    // 1) casts + weight transposes
    cast_f16<<<4096, 256, 0, stream>>>(x, xb, L_ * D_);
    transpose_cast<<<dim3(2048 / 32, 2048 / 32), 256, 0, stream>>>(Wq, Wtqkv, D_, 2048);
    transpose_cast<<<dim3(512 / 32, 2048 / 32), 256, 0, stream>>>(Wk, Wtqkv + (size_t)2048 * D_, D_, 512);
    transpose_cast<<<dim3(512 / 32, 2048 / 32), 256, 0, stream>>>(Wv, Wtqkv + (size_t)2560 * D_, D_, 512);
    transpose_cast<<<dim3(2048 / 32, 2048 / 32), 256, 0, stream>>>(Wo, Wto, 2048, 2048);

    // 2) fused QKV projection (f16 out)
    gemm_mfma<1><<<dim3(QKVW / 128, L_ / 128), 256, 0, stream>>>(xb, Wtqkv, qkv, L_, QKVW, D_);

    // 3) RMSNorm + RoPE in place
    norm_rope_h<<<L_ * 12, 256, 0, stream>>>(qkv, q_scale, k_scale, positions);

    // 4) flash MFMA attention
    attn_mfma<<<(L_ / 32) * H_, 256, 0, stream>>>(qkv, ao);

    // 5) output projection (fp32 out)
    gemm_mfma<0><<<dim3(D_ / 128, L_ / 128), 256, 0, stream>>>(ao, Wto, out, L_, D_, 2048);
}

// Round 4
// 389.381 us; speedup vs baseline: 6.4535x; 1.0305x over previous
//
#include <hip/hip_runtime.h>
#include <hip/hip_bf16.h>
#include <math.h>
#include <stdint.h>

#define L_      4096
#define D_      2048
#define H_      8
#define KVH_    2
#define HD_     256
#define WINDOW_ 512
#define QKVW    3072   // 2048 q + 512 k + 512 v

typedef __attribute__((ext_vector_type(8))) _Float16 f16x8;
typedef __attribute__((ext_vector_type(4))) short s16x4;
typedef __attribute__((ext_vector_type(4))) float f32x4;

__device__ __forceinline__ short f2h(float f) {
    _Float16 h = (_Float16)f;           // RNE
    return *reinterpret_cast<short*>(&h);
}
__device__ __forceinline__ float h2f(short s) {
    _Float16 h = *reinterpret_cast<_Float16*>(&s);
    return (float)h;
}

// async global->LDS 16B per lane; lds base must be wave-uniform
__device__ __forceinline__ void gl2lds16(const void* g, void* l) {
    __builtin_amdgcn_global_load_lds(
        (const __attribute__((address_space(1))) uint32_t*)g,
        (__attribute__((address_space(3))) uint32_t*)l, 16, 0, 0);
}

// ---------------------------------------------------------------------------
// cast fp32 -> fp16 (bits in short), 8 elems/thread
// ---------------------------------------------------------------------------
__global__ __launch_bounds__(256) void cast_f16(const float* __restrict__ X,
                                                short* __restrict__ Y, int n) {
    int idx = (blockIdx.x * 256 + threadIdx.x) * 8;
    if (idx >= n) return;
    float4 a = *(const float4*)(X + idx);
    float4 b = *(const float4*)(X + idx + 4);
    s16x4 o0, o1;
    o0[0]=f2h(a.x); o0[1]=f2h(a.y); o0[2]=f2h(a.z); o0[3]=f2h(a.w);
    o1[0]=f2h(b.x); o1[1]=f2h(b.y); o1[2]=f2h(b.z); o1[3]=f2h(b.w);
    *(s16x4*)(Y + idx)     = o0;
    *(s16x4*)(Y + idx + 4) = o1;
}

// ---------------------------------------------------------------------------
// transpose-cast: W fp32 [K][N] -> Wt fp16 [N][K]
// ---------------------------------------------------------------------------
__global__ __launch_bounds__(256) void transpose_cast(const float* __restrict__ W,
                                                      short* __restrict__ Wt,
                                                      int K, int N) {
    __shared__ float tl[32][33];
    int t = threadIdx.x;
    int c = t & 31, r4 = (t >> 5) * 4;
    int k0 = blockIdx.y * 32, n0 = blockIdx.x * 32;
#pragma unroll
    for (int i = 0; i < 4; ++i)
        tl[r4 + i][c] = W[(size_t)(k0 + r4 + i) * N + n0 + c];
    __syncthreads();
#pragma unroll
    for (int i = 0; i < 4; ++i)
        Wt[(size_t)(n0 + r4 + i) * K + k0 + c] = f2h(tl[c][r4 + i]);
}

// ---------------------------------------------------------------------------
// fp16 MFMA GEMM (m97 structure): C[M][N] = A[M][K] * Bt[N][K]^T
// ---------------------------------------------------------------------------
template <int OUT_HALF>
__global__ __launch_bounds__(256) void gemm_mfma(const short* __restrict__ A,
                                                 const short* __restrict__ Bt,
                                                 void* __restrict__ Cout,
                                                 int M, int N, int K) {
    __shared__ short As[128][32];
    __shared__ short Bs[128][32];

    const int tid = threadIdx.x;
    const int w = tid >> 6, lane = tid & 63;
    const int lq = lane & 15, quad = lane >> 4;
    const int bm = blockIdx.y * 128, bn = blockIdx.x * 128;
    const int wm = (w & 1) * 64, wn = (w >> 1) * 64;
    const int gr = lane >> 2;
    const int gc = (lane & 3) * 8;

    f32x4 acc[4][4];
#pragma unroll
    for (int i = 0; i < 4; ++i)
#pragma unroll
        for (int j = 0; j < 4; ++j) acc[i][j] = 0;

    for (int k0 = 0; k0 < K; k0 += 32) {
#pragma unroll
        for (int c = 0; c < 2; ++c) {
            int r0 = c * 64 + w * 16;
            gl2lds16(A  + (size_t)(bm + r0 + gr) * K + k0 + gc, &As[r0][0]);
            gl2lds16(Bt + (size_t)(bn + r0 + gr) * K + k0 + gc, &Bs[r0][0]);
        }
        __syncthreads();

        f16x8 af[4], bfr[4];
#pragma unroll
        for (int i = 0; i < 4; ++i) af[i]  = *(const f16x8*)&As[wm + i * 16 + lq][quad * 8];
#pragma unroll
        for (int j = 0; j < 4; ++j) bfr[j] = *(const f16x8*)&Bs[wn + j * 16 + lq][quad * 8];
#pragma unroll
        for (int i = 0; i < 4; ++i)
#pragma unroll
            for (int j = 0; j < 4; ++j)
                acc[i][j] = __builtin_amdgcn_mfma_f32_16x16x32_f16(af[i], bfr[j], acc[i][j], 0, 0, 0);
        __syncthreads();
    }

#pragma unroll
    for (int i = 0; i < 4; ++i)
#pragma unroll
        for (int r = 0; r < 4; ++r) {
            int row = bm + wm + i * 16 + quad * 4 + r;
#pragma unroll
            for (int j = 0; j < 4; ++j) {
                int col = bn + wn + j * 16 + lq;
                float v = acc[i][j][r];
                if (OUT_HALF) ((short*)Cout)[(size_t)row * N + col] = f2h(v);
                else          ((float*)Cout)[(size_t)row * N + col] = v;
            }
        }
}

// ---------------------------------------------------------------------------
// RMSNorm (+scale) (+RoPE) in place on fp16 qkv [L][3072].
// rows 0-7 = q heads, 8-9 = k heads, 10-11 = v heads
// ---------------------------------------------------------------------------
__global__ __launch_bounds__(256) void norm_rope_h(short* __restrict__ qkv,
                                                   const float* __restrict__ q_scale,
                                                   const float* __restrict__ k_scale,
                                                   const int* __restrict__ positions) {
    const int row = blockIdx.x;
    const int token = row / 12, ridx = row % 12;
    short* p = qkv + (size_t)token * QKVW + ridx * HD_;
    const int d = threadIdx.x;

    float val = h2f(p[d]);
    float ss = val * val;
#pragma unroll
    for (int off = 32; off > 0; off >>= 1) ss += __shfl_down(ss, off);
    __shared__ float wss[4];
    __shared__ float xs[HD_];
    if ((d & 63) == 0) wss[d >> 6] = ss;
    __syncthreads();
    const float var = (wss[0] + wss[1] + wss[2] + wss[3]) * (1.0f / (float)HD_);
    float xn = val * rsqrtf(var + 1e-6f);
    if (ridx < 8)       xn *= q_scale[d];
    else if (ridx < 10) xn *= k_scale[d];

    if (ridx >= 10) { p[d] = f2h(xn); return; }   // v: norm only

    xs[d] = xn;
    __syncthreads();
    const int pos = positions[token];
    const int i = d & 127;
    const float fe = (float)(2 * i) * (1.0f / (float)HD_);
    // 1/timescale = BASE^(-fe) = exp(-fe * ln(10000))
    const float inv_ts = __expf(fe * -9.210340371976184f);
    const float ang = (float)pos * inv_ts;
    float s, c;
    __sincosf(ang, &s, &c);
    float outv = (d < 128) ? (xn * c - xs[d + 128] * s)
                           : (xn * c + xs[d - 128] * s);
    p[d] = f2h(outv);
}

// ---------------------------------------------------------------------------
// V transpose: normalized V from qkv -> Vt_glob[g][d][L] (fp16)
// block = (token-tile of 64, group g), 256 threads
// ---------------------------------------------------------------------------
__global__ __launch_bounds__(256) void vt_prep(const short* __restrict__ qkv,
                                               short* __restrict__ vtg) {
    const int tok0 = blockIdx.x * 64;
    const int g = blockIdx.y;
    const int tid = threadIdx.x;
    __shared__ short Vs[64][264];
#pragma unroll
    for (int i = 0; i < 8; ++i) {
        int f = (tid + i * 256) * 8;        // flat short idx in 64x256 tile
        int tok = f >> 8, d = f & 255;
        *(int4*)&Vs[tok][d] =
            *(const int4*)(qkv + (size_t)(tok0 + tok) * QKVW + 2560 + g * HD_ + d);
    }
    __syncthreads();
    const int d = tid;
    short tmp[64];
#pragma unroll
    for (int j = 0; j < 64; ++j) tmp[j] = Vs[j][d];
    short* dst = vtg + ((size_t)g * HD_ + d) * L_ + tok0;
#pragma unroll
    for (int c = 0; c < 8; ++c)
        *(int4*)(dst + c * 8) = *(const int4*)&tmp[c * 8];
}

// ---------------------------------------------------------------------------
// Flash MFMA attention v2.
// Block = (q-tile of 16, kv-group g), 256 threads; wave w = head g*4+w.
// K/V staged once per block per 32-key tile, shared by all 4 heads.
// Softmax fully register-resident (C-layout rows == O rows); 2 barriers/tile.
// ---------------------------------------------------------------------------
__global__ __launch_bounds__(256) void attn_mfma(const short* __restrict__ qkv,
                                                 const short* __restrict__ vtg,
                                                 short* __restrict__ ao) {
    const int bx = blockIdx.x;
    const int g = bx & 1, qt = bx >> 1;
    const int q0 = qt * 16;
    const int tid = threadIdx.x;
    const int w = tid >> 6, lane = tid & 63;
    const int lq = lane & 15, quad = lane >> 4;
    const int h = g * 4 + w;

    __shared__ short Ks[32][264];        // rows 528B (16B-mult), bank-uniform frags
    __shared__ short Vt[256][40];        // V^T tile, rows 80B, bank-uniform
    __shared__ short pP[4][16][40];      // per-wave P buffer (A-layout rows)

    // Q A-fragments: A[m=lq][k=f*32+quad*8+j], rows q0+lq, head h
    f16x8 qf[8];
    {
        const short* qrow = qkv + (size_t)(q0 + lq) * QKVW + h * HD_;
#pragma unroll
        for (int f = 0; f < 8; ++f)
            qf[f] = *(const f16x8*)(qrow + f * 32 + quad * 8);
    }

    float m_run[4], l_run[4];
#pragma unroll
    for (int r = 0; r < 4; ++r) { m_run[r] = -INFINITY; l_run[r] = 0.0f; }

    f32x4 accO[16];
#pragma unroll
    for (int dt = 0; dt < 16; ++dt) accO[dt] = 0;

    const short* kcol = qkv + 2048 + g * HD_;
    const short* vrow = vtg + (size_t)g * HD_ * L_;

    for (int kt = 0; kt < 17; ++kt) {
        const int kbase = q0 - WINDOW_ + kt * 32;       // multiple of 16
        if (kbase + 32 <= 0) continue;                  // block-uniform

        // --- stage K tile [32 keys][256 d]: thread = (row, 64B chunk) ---
        {
            const int row = tid >> 3;
            const int co = (tid & 7) * 32;
            int kj = kbase + row;
            kj = min(max(kj, 0), L_ - 1);               // clamped rows are masked
            const short* src = kcol + (size_t)kj * QKVW + co;
            short* dst = &Ks[row][co];
#pragma unroll
            for (int u = 0; u < 4; ++u)
                *(int4*)(dst + u * 8) = *(const int4*)(src + u * 8);
        }
        // --- stage V^T tile [256 d][32 keys]: thread = d, 4 int4 rows ---
        {
            const short* src = vrow + (size_t)tid * L_;
#pragma unroll
            for (int c = 0; c < 4; ++c) {
                int ck = kbase + c * 8;                 // multiple of 8: no straddle
                ck = min(max(ck, 0), L_ - 8);
                *(int4*)&Vt[tid][c * 8] = *(const int4*)(src + ck);
            }
        }
        __syncthreads();

        // --- S = Q K^T: wave computes 16q x 32k for its head ---
        f32x4 sacc0 = 0, sacc1 = 0;
#pragma unroll
        for (int f = 0; f < 8; ++f) {
            f16x8 k0 = *(const f16x8*)&Ks[lq][f * 32 + quad * 8];
            f16x8 k1 = *(const f16x8*)&Ks[16 + lq][f * 32 + quad * 8];
            sacc0 = __builtin_amdgcn_mfma_f32_16x16x32_f16(qf[f], k0, sacc0, 0, 0, 0);
            sacc1 = __builtin_amdgcn_mfma_f32_16x16x32_f16(qf[f], k1, sacc1, 0, 0, 0);
        }

        // --- register softmax: lane holds rows quad*4+r, cols lq / 16+lq ---
        float alpha[4];
        const int k0i = kbase + lq;
        const int k1i = kbase + 16 + lq;
#pragma unroll
        for (int r = 0; r < 4; ++r) {
            const int qi = q0 + quad * 4 + r;
            const bool v0 = (k0i >= 0) && (k0i <= qi) && (k0i > qi - WINDOW_);
            const bool v1 = (k1i >= 0) && (k1i <= qi) && (k1i > qi - WINDOW_);
            float s0 = v0 ? sacc0[r] : -INFINITY;
            float s1 = v1 ? sacc1[r] : -INFINITY;
            float mt = fmaxf(s0, s1);
#pragma unroll
            for (int off = 1; off < 16; off <<= 1) mt = fmaxf(mt, __shfl_xor(mt, off));
            const float mn = fmaxf(m_run[r], mt);
            const float a = (mn == -INFINITY) ? 1.0f : __expf(m_run[r] - mn);
            const float p0 = v0 ? __expf(s0 - mn) : 0.0f;
            const float p1 = v1 ? __expf(s1 - mn) : 0.0f;
            float rs = p0 + p1;
#pragma unroll
            for (int off = 1; off < 16; off <<= 1) rs += __shfl_xor(rs, off);
            m_run[r] = mn;
            l_run[r] = l_run[r] * a + rs;
            alpha[r] = a;
            pP[w][quad * 4 + r][lq]      = f2h(p0);
            pP[w][quad * 4 + r][16 + lq] = f2h(p1);
        }

        // --- PV: O[16q][256d] += P V ; A-frag from own-wave pP (lgkm wait only)
        {
            f16x8 pf = *(const f16x8*)&pP[w][lq][quad * 8];
#pragma unroll
            for (int dt = 0; dt < 16; ++dt) {
                f16x8 vf = *(const f16x8*)&Vt[dt * 16 + lq][quad * 8];
                f32x4 t = accO[dt];
#pragma unroll
                for (int r = 0; r < 4; ++r) t[r] *= alpha[r];
                accO[dt] = __builtin_amdgcn_mfma_f32_16x16x32_f16(pf, vf, t, 0, 0, 0);
            }
        }
        __syncthreads();   // Ks/Vt consumed before next staging
    }

    // --- epilogue: O rows quad*4+r, cols dt*16+lq ---
    float inv[4];
#pragma unroll
    for (int r = 0; r < 4; ++r) inv[r] = 1.0f / l_run[r];
#pragma unroll
    for (int dt = 0; dt < 16; ++dt)
#pragma unroll
        for (int r = 0; r < 4; ++r) {
            const int row = q0 + quad * 4 + r;
            ao[(size_t)row * 2048 + h * HD_ + dt * 16 + lq] = f2h(accO[dt][r] * inv[r]);
        }
}

// ---------------------------------------------------------------------------
extern "C" void kernel_launch(void* const* d_in, const int* in_sizes, int n_in,
                              void* d_out, int out_size, void* d_ws, size_t ws_size,
                              hipStream_t stream) {
    const float* x         = (const float*)d_in[0];
    const int*   positions = (const int*)d_in[1];
    const float* Wq        = (const float*)d_in[2];
    const float* Wk        = (const float*)d_in[3];
    const float* Wv        = (const float*)d_in[4];
    const float* Wo        = (const float*)d_in[5];
    const float* q_scale   = (const float*)d_in[6];
    const float* k_scale   = (const float*)d_in[7];
    float*       out       = (float*)d_out;

    // workspace layout (bytes, ~80 MB total)
    char* ws = (char*)d_ws;
    short* xb    = (short*)(ws);                 // [4096][2048] f16   16 MB
    short* qkv   = (short*)(ws + 16777216);      // [4096][3072] f16   24 MB
    short* ao    = (short*)(ws + 41943040);      // [4096][2048] f16   16 MB
    short* Wtqkv = (short*)(ws + 58720256);      // [3072][2048] f16   12 MB
    short* Wto   = (short*)(ws + 71303168);      // [2048][2048] f16    8 MB
    short* vtg   = xb;                           // aliases xb (dead after QKV GEMM), 4 MB

    // 1) casts + weight transposes
    cast_f16<<<4096, 256, 0, stream>>>(x, xb, L_ * D_);
    transpose_cast<<<dim3(2048 / 32, 2048 / 32), 256, 0, stream>>>(Wq, Wtqkv, D_, 2048);
    transpose_cast<<<dim3(512 / 32, 2048 / 32), 256, 0, stream>>>(Wk, Wtqkv + (size_t)2048 * D_, D_, 512);
    transpose_cast<<<dim3(512 / 32, 2048 / 32), 256, 0, stream>>>(Wv, Wtqkv + (size_t)2560 * D_, D_, 512);
    transpose_cast<<<dim3(2048 / 32, 2048 / 32), 256, 0, stream>>>(Wo, Wto, 2048, 2048);

    // 2) fused QKV projection (f16 out)
    gemm_mfma<1><<<dim3(QKVW / 128, L_ / 128), 256, 0, stream>>>(xb, Wtqkv, qkv, L_, QKVW, D_);

    // 3) RMSNorm + RoPE in place
    norm_rope_h<<<L_ * 12, 256, 0, stream>>>(qkv, q_scale, k_scale, positions);

    // 4) V transpose to [g][d][L] (into xb region, now dead)
    vt_prep<<<dim3(L_ / 64, KVH_), 256, 0, stream>>>(qkv, vtg);

    // 5) flash MFMA attention v2
    attn_mfma<<<(L_ / 16) * KVH_, 256, 0, stream>>>(qkv, vtg, ao);

    // 6) output projection (fp32 out)
    gemm_mfma<0><<<dim3(D_ / 128, L_ / 128), 256, 0, stream>>>(ao, Wto, out, L_, D_, 2048);
}

// Round 5
// 352.398 us; speedup vs baseline: 7.1307x; 1.1049x over previous
//
#include <hip/hip_runtime.h>
#include <hip/hip_bf16.h>
#include <math.h>
#include <stdint.h>

#define L_      4096
#define D_      2048
#define H_      8
#define KVH_    2
#define HD_     256
#define WINDOW_ 512
#define QKVW    3072   // 2048 q + 512 k + 512 v

typedef __attribute__((ext_vector_type(8))) _Float16 f16x8;
typedef __attribute__((ext_vector_type(4))) _Float16 f16x4;
typedef __attribute__((ext_vector_type(4))) short s16x4;
typedef __attribute__((ext_vector_type(4))) float f32x4;

__device__ __forceinline__ short f2h(float f) {
    _Float16 h = (_Float16)f;           // RNE
    return *reinterpret_cast<short*>(&h);
}
__device__ __forceinline__ float h2f(short s) {
    _Float16 h = *reinterpret_cast<_Float16*>(&s);
    return (float)h;
}

// async global->LDS 16B per lane; lds base must be wave-uniform
__device__ __forceinline__ void gl2lds16(const void* g, void* l) {
    __builtin_amdgcn_global_load_lds(
        (const __attribute__((address_space(1))) uint32_t*)g,
        (__attribute__((address_space(3))) uint32_t*)l, 16, 0, 0);
}

// ---------------------------------------------------------------------------
// cast fp32 -> fp16 (bits in short), 8 elems/thread
// ---------------------------------------------------------------------------
__global__ __launch_bounds__(256) void cast_f16(const float* __restrict__ X,
                                                short* __restrict__ Y, int n) {
    int idx = (blockIdx.x * 256 + threadIdx.x) * 8;
    if (idx >= n) return;
    float4 a = *(const float4*)(X + idx);
    float4 b = *(const float4*)(X + idx + 4);
    s16x4 o0, o1;
    o0[0]=f2h(a.x); o0[1]=f2h(a.y); o0[2]=f2h(a.z); o0[3]=f2h(a.w);
    o1[0]=f2h(b.x); o1[1]=f2h(b.y); o1[2]=f2h(b.z); o1[3]=f2h(b.w);
    *(s16x4*)(Y + idx)     = o0;
    *(s16x4*)(Y + idx + 4) = o1;
}

// ---------------------------------------------------------------------------
// transpose-cast: W fp32 [K][N] -> Wt fp16 [N][K]
// ---------------------------------------------------------------------------
__global__ __launch_bounds__(256) void transpose_cast(const float* __restrict__ W,
                                                      short* __restrict__ Wt,
                                                      int K, int N) {
    __shared__ float tl[32][33];
    int t = threadIdx.x;
    int c = t & 31, r4 = (t >> 5) * 4;
    int k0 = blockIdx.y * 32, n0 = blockIdx.x * 32;
#pragma unroll
    for (int i = 0; i < 4; ++i)
        tl[r4 + i][c] = W[(size_t)(k0 + r4 + i) * N + n0 + c];
    __syncthreads();
#pragma unroll
    for (int i = 0; i < 4; ++i)
        Wt[(size_t)(n0 + r4 + i) * K + k0 + c] = f2h(tl[c][r4 + i]);
}

// ---------------------------------------------------------------------------
// fp16 MFMA GEMM (m97 structure): C[M][N] = A[M][K] * Bt[N][K]^T
// ---------------------------------------------------------------------------
template <int OUT_HALF>
__global__ __launch_bounds__(256) void gemm_mfma(const short* __restrict__ A,
                                                 const short* __restrict__ Bt,
                                                 void* __restrict__ Cout,
                                                 int M, int N, int K) {
    __shared__ short As[128][32];
    __shared__ short Bs[128][32];

    const int tid = threadIdx.x;
    const int w = tid >> 6, lane = tid & 63;
    const int lq = lane & 15, quad = lane >> 4;
    const int bm = blockIdx.y * 128, bn = blockIdx.x * 128;
    const int wm = (w & 1) * 64, wn = (w >> 1) * 64;
    const int gr = lane >> 2;
    const int gc = (lane & 3) * 8;

    f32x4 acc[4][4];
#pragma unroll
    for (int i = 0; i < 4; ++i)
#pragma unroll
        for (int j = 0; j < 4; ++j) acc[i][j] = 0;

    for (int k0 = 0; k0 < K; k0 += 32) {
#pragma unroll
        for (int c = 0; c < 2; ++c) {
            int r0 = c * 64 + w * 16;
            gl2lds16(A  + (size_t)(bm + r0 + gr) * K + k0 + gc, &As[r0][0]);
            gl2lds16(Bt + (size_t)(bn + r0 + gr) * K + k0 + gc, &Bs[r0][0]);
        }
        __syncthreads();

        f16x8 af[4], bfr[4];
#pragma unroll
        for (int i = 0; i < 4; ++i) af[i]  = *(const f16x8*)&As[wm + i * 16 + lq][quad * 8];
#pragma unroll
        for (int j = 0; j < 4; ++j) bfr[j] = *(const f16x8*)&Bs[wn + j * 16 + lq][quad * 8];
#pragma unroll
        for (int i = 0; i < 4; ++i)
#pragma unroll
            for (int j = 0; j < 4; ++j)
                acc[i][j] = __builtin_amdgcn_mfma_f32_16x16x32_f16(af[i], bfr[j], acc[i][j], 0, 0, 0);
        __syncthreads();
    }

#pragma unroll
    for (int i = 0; i < 4; ++i)
#pragma unroll
        for (int r = 0; r < 4; ++r) {
            int row = bm + wm + i * 16 + quad * 4 + r;
#pragma unroll
            for (int j = 0; j < 4; ++j) {
                int col = bn + wn + j * 16 + lq;
                float v = acc[i][j][r];
                if (OUT_HALF) ((short*)Cout)[(size_t)row * N + col] = f2h(v);
                else          ((float*)Cout)[(size_t)row * N + col] = v;
            }
        }
}

// ---------------------------------------------------------------------------
// RMSNorm (+scale) (+RoPE) in place on fp16 qkv [L][3072].
// rows 0-7 = q heads, 8-9 = k heads, 10-11 = v heads
// ---------------------------------------------------------------------------
__global__ __launch_bounds__(256) void norm_rope_h(short* __restrict__ qkv,
                                                   const float* __restrict__ q_scale,
                                                   const float* __restrict__ k_scale,
                                                   const int* __restrict__ positions) {
    const int row = blockIdx.x;
    const int token = row / 12, ridx = row % 12;
    short* p = qkv + (size_t)token * QKVW + ridx * HD_;
    const int d = threadIdx.x;

    float val = h2f(p[d]);
    float ss = val * val;
#pragma unroll
    for (int off = 32; off > 0; off >>= 1) ss += __shfl_down(ss, off);
    __shared__ float wss[4];
    __shared__ float xs[HD_];
    if ((d & 63) == 0) wss[d >> 6] = ss;
    __syncthreads();
    const float var = (wss[0] + wss[1] + wss[2] + wss[3]) * (1.0f / (float)HD_);
    float xn = val * rsqrtf(var + 1e-6f);
    if (ridx < 8)       xn *= q_scale[d];
    else if (ridx < 10) xn *= k_scale[d];

    if (ridx >= 10) { p[d] = f2h(xn); return; }   // v: norm only

    xs[d] = xn;
    __syncthreads();
    const int pos = positions[token];
    const int i = d & 127;
    const float fe = (float)(2 * i) * (1.0f / (float)HD_);
    const float inv_ts = __expf(fe * -9.210340371976184f);   // BASE^-fe
    const float ang = (float)pos * inv_ts;
    float s, c;
    __sincosf(ang, &s, &c);
    float outv = (d < 128) ? (xn * c - xs[d + 128] * s)
                           : (xn * c + xs[d - 128] * s);
    p[d] = f2h(outv);
}

// ---------------------------------------------------------------------------
// V transpose: normalized V from qkv -> Vt_glob[g][d][L] (fp16)
// ---------------------------------------------------------------------------
__global__ __launch_bounds__(256) void vt_prep(const short* __restrict__ qkv,
                                               short* __restrict__ vtg) {
    const int tok0 = blockIdx.x * 64;
    const int g = blockIdx.y;
    const int tid = threadIdx.x;
    __shared__ short Vs[64][264];
#pragma unroll
    for (int i = 0; i < 8; ++i) {
        int f = (tid + i * 256) * 8;
        int tok = f >> 8, d = f & 255;
        *(int4*)&Vs[tok][d] =
            *(const int4*)(qkv + (size_t)(tok0 + tok) * QKVW + 2560 + g * HD_ + d);
    }
    __syncthreads();
    const int d = tid;
    short tmp[64];
#pragma unroll
    for (int j = 0; j < 64; ++j) tmp[j] = Vs[j][d];
    short* dst = vtg + ((size_t)g * HD_ + d) * L_ + tok0;
#pragma unroll
    for (int c = 0; c < 8; ++c)
        *(int4*)(dst + c * 8) = *(const int4*)&tmp[c * 8];
}

// ---------------------------------------------------------------------------
// Flash MFMA attention v3 — S^T layout (operand swap).
// Block = (16-query tile, kv-group g), 256 threads; wave w = head g*4+w.
// S^T = K·Q^T: C-layout puts q on lanes (col=lq), keys on rows (quad*4+r).
// Softmax: 7 in-reg ops + 2 shfl_xor per 32-key tile; m/l per-lane scalars.
// exp(S^T) C-layout regs == B-frag of mfma_f32_16x16x16_f16 -> PV with no
// LDS round-trip: O^T += V^T·P^T, V^T A-frags = ds_read_b64 from Vt tile.
// ---------------------------------------------------------------------------
__global__ __launch_bounds__(256) void attn_mfma(const short* __restrict__ qkv,
                                                 const short* __restrict__ vtg,
                                                 short* __restrict__ ao) {
    const int bx = blockIdx.x;
    const int g = bx & 1, qt = bx >> 1;
    const int q0 = qt * 16;
    const int tid = threadIdx.x;
    const int w = tid >> 6, lane = tid & 63;
    const int lq = lane & 15, quad = lane >> 4;
    const int h = g * 4 + w;

    // flat LDS; Ks/Vt overlap the per-wave epilogue regions
    __shared__ short lds[18688];
    short (*Ks)[264] = (short (*)[264])lds;            // [32][264]
    short (*Vt)[40]  = (short (*)[40])(lds + 8448);    // [256][40]

    // Q B-fragments: B[k=quad*8+j][n=lq] = Q[q0+lq][f*32+quad*8+j]
    f16x8 qf[8];
    {
        const short* qrow = qkv + (size_t)(q0 + lq) * QKVW + h * HD_;
#pragma unroll
        for (int f = 0; f < 8; ++f)
            qf[f] = *(const f16x8*)(qrow + f * 32 + quad * 8);
    }

    float m_run = -INFINITY, l_run = 0.0f;   // per-lane: query q0+lq

    f32x4 accO[16];                          // O^T[d=dt*16+quad*4+r][q=lq]
#pragma unroll
    for (int dt = 0; dt < 16; ++dt) accO[dt] = 0;

    const short* kcol = qkv + 2048 + g * HD_;
    const short* vrow = vtg + (size_t)g * HD_ * L_;
    const int qi = q0 + lq;

    for (int kt = 0; kt < 17; ++kt) {
        const int kbase = q0 - WINDOW_ + kt * 32;
        if (kbase + 32 <= 0) continue;                  // block-uniform

        // --- stage K tile [32 keys][256 d] ---
        {
            const int row = tid >> 3;
            const int co = (tid & 7) * 32;
            int kj = kbase + row;
            kj = min(max(kj, 0), L_ - 1);               // clamped rows are masked
            const short* src = kcol + (size_t)kj * QKVW + co;
            short* dst = &Ks[row][co];
#pragma unroll
            for (int u = 0; u < 4; ++u)
                *(int4*)(dst + u * 8) = *(const int4*)(src + u * 8);
        }
        // --- stage V^T tile [256 d][32 keys] ---
        {
            const short* src = vrow + (size_t)tid * L_;
#pragma unroll
            for (int c = 0; c < 4; ++c) {
                int ck = kbase + c * 8;
                ck = min(max(ck, 0), L_ - 8);
                *(int4*)&Vt[tid][c * 8] = *(const int4*)(src + ck);
            }
        }
        __syncthreads();

        // --- S^T = K Q^T : two 16-key subtiles ---
        f32x4 st0 = 0, st1 = 0;
#pragma unroll
        for (int f = 0; f < 8; ++f) {
            f16x8 kf0 = *(const f16x8*)&Ks[lq][f * 32 + quad * 8];
            f16x8 kf1 = *(const f16x8*)&Ks[16 + lq][f * 32 + quad * 8];
            st0 = __builtin_amdgcn_mfma_f32_16x16x32_f16(kf0, qf[f], st0, 0, 0, 0);
            st1 = __builtin_amdgcn_mfma_f32_16x16x32_f16(kf1, qf[f], st1, 0, 0, 0);
        }

        // --- register softmax (keys on (quad,r), query = lq) ---
        const int kA = kbase + quad * 4;        // keys for st0 regs
        const int kB = kA + 16;                 // keys for st1 regs
        float sv[8]; bool vd[8];
#pragma unroll
        for (int r = 0; r < 4; ++r) {
            int ka = kA + r, kb = kB + r;
            vd[r]     = (ka >= 0) && (ka <= qi) && (ka > qi - WINDOW_);
            vd[4 + r] = (kb >= 0) && (kb <= qi) && (kb > qi - WINDOW_);
            sv[r]     = vd[r]     ? st0[r] : -INFINITY;
            sv[4 + r] = vd[4 + r] ? st1[r] : -INFINITY;
        }
        float mt = sv[0];
#pragma unroll
        for (int i = 1; i < 8; ++i) mt = fmaxf(mt, sv[i]);
        mt = fmaxf(mt, __shfl_xor(mt, 16));
        mt = fmaxf(mt, __shfl_xor(mt, 32));
        const float mn = fmaxf(m_run, mt);
        const float alpha = (mn == -INFINITY) ? 1.0f : __expf(m_run - mn);
        float pv[8], rs = 0.0f;
#pragma unroll
        for (int i = 0; i < 8; ++i) {
            pv[i] = vd[i] ? __expf(sv[i] - mn) : 0.0f;
            rs += pv[i];
        }
        rs += __shfl_xor(rs, 16);
        rs += __shfl_xor(rs, 32);
        m_run = mn;
        l_run = l_run * alpha + rs;

        // P^T B-frags (B[k=quad*4+i][n=lq]) straight from registers
        f16x4 p0, p1;
#pragma unroll
        for (int i = 0; i < 4; ++i) { p0[i] = (_Float16)pv[i]; p1[i] = (_Float16)pv[4 + i]; }

        // --- PV: O^T[d][q] += V^T[d][k] P^T[k][q], 16x16x16 MFMAs ---
#pragma unroll
        for (int dt = 0; dt < 16; ++dt) {
            f16x4 v0 = *(const f16x4*)&Vt[dt * 16 + lq][quad * 4];
            f16x4 v1 = *(const f16x4*)&Vt[dt * 16 + lq][16 + quad * 4];
            f32x4 t = accO[dt];
#pragma unroll
            for (int r = 0; r < 4; ++r) t[r] *= alpha;
            t = __builtin_amdgcn_mfma_f32_16x16x16f16(v0, p0, t, 0, 0, 0);
            t = __builtin_amdgcn_mfma_f32_16x16x16f16(v1, p1, t, 0, 0, 0);
            accO[dt] = t;
        }
        __syncthreads();   // Ks/Vt consumed before next staging
    }

    // --- epilogue: untranspose O^T via per-wave LDS region, then coalesced store
    const float inv = 1.0f / l_run;            // per-query (lane) scalar
    short* myE = lds + w * 4224;               // 16 rows x 264 shorts per wave
#pragma unroll
    for (int dt = 0; dt < 16; ++dt) {
        f16x4 e;
#pragma unroll
        for (int r = 0; r < 4; ++r) e[r] = (_Float16)(accO[dt][r] * inv);
        *(f16x4*)&myE[lq * 264 + dt * 16 + quad * 4] = e;   // O[q=lq][d]
    }
    // same-wave read-back (lgkmcnt only), coalesced global store
    {
        const int row = lane >> 2;             // 16 q rows
        const int c0 = (lane & 3) * 64;        // 4 x 64-short segments
        short* orow = ao + (size_t)(q0 + row) * 2048 + h * HD_ + c0;
#pragma unroll
        for (int u = 0; u < 8; ++u)
            *(int4*)(orow + u * 8) = *(const int4*)&myE[row * 264 + c0 + u * 8];
    }
}

// ---------------------------------------------------------------------------
extern "C" void kernel_launch(void* const* d_in, const int* in_sizes, int n_in,
                              void* d_out, int out_size, void* d_ws, size_t ws_size,
                              hipStream_t stream) {
    const float* x         = (const float*)d_in[0];
    const int*   positions = (const int*)d_in[1];
    const float* Wq        = (const float*)d_in[2];
    const float* Wk        = (const float*)d_in[3];
    const float* Wv        = (const float*)d_in[4];
    const float* Wo        = (const float*)d_in[5];
    const float* q_scale   = (const float*)d_in[6];
    const float* k_scale   = (const float*)d_in[7];
    float*       out       = (float*)d_out;

    // workspace layout (bytes, ~80 MB total)
    char* ws = (char*)d_ws;
    short* xb    = (short*)(ws);                 // [4096][2048] f16   16 MB
    short* qkv   = (short*)(ws + 16777216);      // [4096][3072] f16   24 MB
    short* ao    = (short*)(ws + 41943040);      // [4096][2048] f16   16 MB
    short* Wtqkv = (short*)(ws + 58720256);      // [3072][2048] f16   12 MB
    short* Wto   = (short*)(ws + 71303168);      // [2048][2048] f16    8 MB
    short* vtg   = xb;                           // aliases xb (dead after QKV GEMM)

    // 1) casts + weight transposes
    cast_f16<<<4096, 256, 0, stream>>>(x, xb, L_ * D_);
    transpose_cast<<<dim3(2048 / 32, 2048 / 32), 256, 0, stream>>>(Wq, Wtqkv, D_, 2048);
    transpose_cast<<<dim3(512 / 32, 2048 / 32), 256, 0, stream>>>(Wk, Wtqkv + (size_t)2048 * D_, D_, 512);
    transpose_cast<<<dim3(512 / 32, 2048 / 32), 256, 0, stream>>>(Wv, Wtqkv + (size_t)2560 * D_, D_, 512);
    transpose_cast<<<dim3(2048 / 32, 2048 / 32), 256, 0, stream>>>(Wo, Wto, 2048, 2048);

    // 2) fused QKV projection (f16 out)
    gemm_mfma<1><<<dim3(QKVW / 128, L_ / 128), 256, 0, stream>>>(xb, Wtqkv, qkv, L_, QKVW, D_);

    // 3) RMSNorm + RoPE in place
    norm_rope_h<<<L_ * 12, 256, 0, stream>>>(qkv, q_scale, k_scale, positions);

    // 4) V transpose to [g][d][L] (into xb region, now dead)
    vt_prep<<<dim3(L_ / 64, KVH_), 256, 0, stream>>>(qkv, vtg);

    // 5) flash MFMA attention v3
    attn_mfma<<<(L_ / 16) * KVH_, 256, 0, stream>>>(qkv, vtg, ao);

    // 6) output projection (fp32 out)
    gemm_mfma<0><<<dim3(D_ / 128, L_ / 128), 256, 0, stream>>>(ao, Wto, out, L_, D_, 2048);
}

// Round 6
// 339.737 us; speedup vs baseline: 7.3965x; 1.0373x over previous
//
#include <hip/hip_runtime.h>
#include <hip/hip_bf16.h>
#include <math.h>
#include <stdint.h>

#define L_      4096
#define D_      2048
#define H_      8
#define KVH_    2
#define HD_     256
#define WINDOW_ 512
#define QKVW    3072   // 2048 q + 512 k + 512 v

typedef __attribute__((ext_vector_type(8))) _Float16 f16x8;
typedef __attribute__((ext_vector_type(4))) _Float16 f16x4;
typedef __attribute__((ext_vector_type(4))) short s16x4;
typedef __attribute__((ext_vector_type(4))) float f32x4;

__device__ __forceinline__ short f2h(float f) {
    _Float16 h = (_Float16)f;           // RNE
    return *reinterpret_cast<short*>(&h);
}
__device__ __forceinline__ float h2f(short s) {
    _Float16 h = *reinterpret_cast<_Float16*>(&s);
    return (float)h;
}

// async global->LDS 16B per lane; lds base must be wave-uniform
__device__ __forceinline__ void gl2lds16(const void* g, void* l) {
    __builtin_amdgcn_global_load_lds(
        (const __attribute__((address_space(1))) uint32_t*)g,
        (__attribute__((address_space(3))) uint32_t*)l, 16, 0, 0);
}

// ---------------------------------------------------------------------------
// cast fp32 -> fp16 (bits in short), 8 elems/thread
// ---------------------------------------------------------------------------
__global__ __launch_bounds__(256) void cast_f16(const float* __restrict__ X,
                                                short* __restrict__ Y, int n) {
    int idx = (blockIdx.x * 256 + threadIdx.x) * 8;
    if (idx >= n) return;
    float4 a = *(const float4*)(X + idx);
    float4 b = *(const float4*)(X + idx + 4);
    s16x4 o0, o1;
    o0[0]=f2h(a.x); o0[1]=f2h(a.y); o0[2]=f2h(a.z); o0[3]=f2h(a.w);
    o1[0]=f2h(b.x); o1[1]=f2h(b.y); o1[2]=f2h(b.z); o1[3]=f2h(b.w);
    *(s16x4*)(Y + idx)     = o0;
    *(s16x4*)(Y + idx + 4) = o1;
}

// ---------------------------------------------------------------------------
// transpose-cast: W fp32 [K][N] -> Wt fp16 [N][K]
// ---------------------------------------------------------------------------
__global__ __launch_bounds__(256) void transpose_cast(const float* __restrict__ W,
                                                      short* __restrict__ Wt,
                                                      int K, int N) {
    __shared__ float tl[32][33];
    int t = threadIdx.x;
    int c = t & 31, r4 = (t >> 5) * 4;
    int k0 = blockIdx.y * 32, n0 = blockIdx.x * 32;
#pragma unroll
    for (int i = 0; i < 4; ++i)
        tl[r4 + i][c] = W[(size_t)(k0 + r4 + i) * N + n0 + c];
    __syncthreads();
#pragma unroll
    for (int i = 0; i < 4; ++i)
        Wt[(size_t)(n0 + r4 + i) * K + k0 + c] = f2h(tl[c][r4 + i]);
}

// ---------------------------------------------------------------------------
// fp16 MFMA GEMM v2: C[M][N] = A[M][K] * Bt[N][K]^T
// 128x128 tile, BK=64 (128B LDS rows), XOR-swizzled chunk placement:
// chunk c of row r lives at slot c^(r&7). Staging applies the swizzle on the
// per-lane GLOBAL address (global_load_lds LDS side is fixed contiguous);
// fragment reads un-swizzle with slot=(f*4+quad)^(lq&7) -> 2-way max (free).
// ---------------------------------------------------------------------------
template <int OUT_HALF>
__global__ __launch_bounds__(256) void gemm_mfma(const short* __restrict__ A,
                                                 const short* __restrict__ Bt,
                                                 void* __restrict__ Cout,
                                                 int M, int N, int K) {
    __shared__ short As[128][64];   // 16 KB each, rows 128B
    __shared__ short Bs[128][64];

    const int tid = threadIdx.x;
    const int w = tid >> 6, lane = tid & 63;
    const int lq = lane & 15, quad = lane >> 4;
    const int bm = blockIdx.y * 128, bn = blockIdx.x * 128;
    const int wm = (w & 1) * 64, wn = (w >> 1) * 64;
    const int lrow = lane >> 3;      // 0..7: row within 8-row staging group
    const int slot = lane & 7;       // 0..7: LDS 16B slot this lane fills

    f32x4 acc[4][4];
#pragma unroll
    for (int i = 0; i < 4; ++i)
#pragma unroll
        for (int j = 0; j < 4; ++j) acc[i][j] = 0;

    for (int k0 = 0; k0 < K; k0 += 64) {
        // stage 128 rows x 128B per matrix; wave stages 8 rows per instr
#pragma unroll
        for (int c = 0; c < 4; ++c) {
            const int r0 = w * 32 + c * 8;            // wave-uniform
            const int row = r0 + lrow;
            const int chunk = slot ^ (row & 7);       // swizzled source chunk
            gl2lds16(A  + (size_t)(bm + row) * K + k0 + chunk * 8, &As[r0][0]);
            gl2lds16(Bt + (size_t)(bn + row) * K + k0 + chunk * 8, &Bs[r0][0]);
        }
        __syncthreads();   // drains vmcnt -> staged data visible

#pragma unroll
        for (int f = 0; f < 2; ++f) {
            const int sA = (((f * 4) + quad) ^ (lq & 7)) * 8;  // un-swizzle
            f16x8 af[4], bfr[4];
#pragma unroll
            for (int i = 0; i < 4; ++i) af[i]  = *(const f16x8*)&As[wm + i * 16 + lq][sA];
#pragma unroll
            for (int j = 0; j < 4; ++j) bfr[j] = *(const f16x8*)&Bs[wn + j * 16 + lq][sA];
#pragma unroll
            for (int i = 0; i < 4; ++i)
#pragma unroll
                for (int j = 0; j < 4; ++j)
                    acc[i][j] = __builtin_amdgcn_mfma_f32_16x16x32_f16(af[i], bfr[j], acc[i][j], 0, 0, 0);
        }
        __syncthreads();
    }

    // epilogue: C/D layout col=lane&15, row=quad*4+reg
#pragma unroll
    for (int i = 0; i < 4; ++i)
#pragma unroll
        for (int r = 0; r < 4; ++r) {
            int row = bm + wm + i * 16 + quad * 4 + r;
#pragma unroll
            for (int j = 0; j < 4; ++j) {
                int col = bn + wn + j * 16 + lq;
                float v = acc[i][j][r];
                if (OUT_HALF) ((short*)Cout)[(size_t)row * N + col] = f2h(v);
                else          ((float*)Cout)[(size_t)row * N + col] = v;
            }
        }
}

// ---------------------------------------------------------------------------
// RMSNorm (+scale) (+RoPE) in place on fp16 qkv [L][3072].
// rows 0-7 = q heads, 8-9 = k heads, 10-11 = v heads
// ---------------------------------------------------------------------------
__global__ __launch_bounds__(256) void norm_rope_h(short* __restrict__ qkv,
                                                   const float* __restrict__ q_scale,
                                                   const float* __restrict__ k_scale,
                                                   const int* __restrict__ positions) {
    const int row = blockIdx.x;
    const int token = row / 12, ridx = row % 12;
    short* p = qkv + (size_t)token * QKVW + ridx * HD_;
    const int d = threadIdx.x;

    float val = h2f(p[d]);
    float ss = val * val;
#pragma unroll
    for (int off = 32; off > 0; off >>= 1) ss += __shfl_down(ss, off);
    __shared__ float wss[4];
    __shared__ float xs[HD_];
    if ((d & 63) == 0) wss[d >> 6] = ss;
    __syncthreads();
    const float var = (wss[0] + wss[1] + wss[2] + wss[3]) * (1.0f / (float)HD_);
    float xn = val * rsqrtf(var + 1e-6f);
    if (ridx < 8)       xn *= q_scale[d];
    else if (ridx < 10) xn *= k_scale[d];

    if (ridx >= 10) { p[d] = f2h(xn); return; }   // v: norm only

    xs[d] = xn;
    __syncthreads();
    const int pos = positions[token];
    const int i = d & 127;
    const float fe = (float)(2 * i) * (1.0f / (float)HD_);
    const float inv_ts = __expf(fe * -9.210340371976184f);   // BASE^-fe
    const float ang = (float)pos * inv_ts;
    float s, c;
    __sincosf(ang, &s, &c);
    float outv = (d < 128) ? (xn * c - xs[d + 128] * s)
                           : (xn * c + xs[d - 128] * s);
    p[d] = f2h(outv);
}

// ---------------------------------------------------------------------------
// V transpose: normalized V from qkv -> Vt_glob[g][d][L] (fp16)
// ---------------------------------------------------------------------------
__global__ __launch_bounds__(256) void vt_prep(const short* __restrict__ qkv,
                                               short* __restrict__ vtg) {
    const int tok0 = blockIdx.x * 64;
    const int g = blockIdx.y;
    const int tid = threadIdx.x;
    __shared__ short Vs[64][264];
#pragma unroll
    for (int i = 0; i < 8; ++i) {
        int f = (tid + i * 256) * 8;
        int tok = f >> 8, d = f & 255;
        *(int4*)&Vs[tok][d] =
            *(const int4*)(qkv + (size_t)(tok0 + tok) * QKVW + 2560 + g * HD_ + d);
    }
    __syncthreads();
    const int d = tid;
    short tmp[64];
#pragma unroll
    for (int j = 0; j < 64; ++j) tmp[j] = Vs[j][d];
    short* dst = vtg + ((size_t)g * HD_ + d) * L_ + tok0;
#pragma unroll
    for (int c = 0; c < 8; ++c)
        *(int4*)(dst + c * 8) = *(const int4*)&tmp[c * 8];
}

// ---------------------------------------------------------------------------
// Flash MFMA attention v3 — S^T layout (operand swap).
// Block = (16-query tile, kv-group g), 256 threads; wave w = head g*4+w.
// S^T = K·Q^T: C-layout puts q on lanes (col=lq), keys on rows (quad*4+r).
// Softmax: 7 in-reg ops + 2 shfl_xor per 32-key tile; m/l per-lane scalars.
// exp(S^T) C-layout regs == B-frag of mfma_f32_16x16x16_f16 -> PV with no
// LDS round-trip: O^T += V^T·P^T, V^T A-frags = ds_read_b64 from Vt tile.
// ---------------------------------------------------------------------------
__global__ __launch_bounds__(256) void attn_mfma(const short* __restrict__ qkv,
                                                 const short* __restrict__ vtg,
                                                 short* __restrict__ ao) {
    const int bx = blockIdx.x;
    const int g = bx & 1, qt = bx >> 1;
    const int q0 = qt * 16;
    const int tid = threadIdx.x;
    const int w = tid >> 6, lane = tid & 63;
    const int lq = lane & 15, quad = lane >> 4;
    const int h = g * 4 + w;

    // flat LDS; Ks/Vt overlap the per-wave epilogue regions
    __shared__ short lds[18688];
    short (*Ks)[264] = (short (*)[264])lds;            // [32][264]
    short (*Vt)[40]  = (short (*)[40])(lds + 8448);    // [256][40]

    // Q B-fragments: B[k=quad*8+j][n=lq] = Q[q0+lq][f*32+quad*8+j]
    f16x8 qf[8];
    {
        const short* qrow = qkv + (size_t)(q0 + lq) * QKVW + h * HD_;
#pragma unroll
        for (int f = 0; f < 8; ++f)
            qf[f] = *(const f16x8*)(qrow + f * 32 + quad * 8);
    }

    float m_run = -INFINITY, l_run = 0.0f;   // per-lane: query q0+lq

    f32x4 accO[16];                          // O^T[d=dt*16+quad*4+r][q=lq]
#pragma unroll
    for (int dt = 0; dt < 16; ++dt) accO[dt] = 0;

    const short* kcol = qkv + 2048 + g * HD_;
    const short* vrow = vtg + (size_t)g * HD_ * L_;
    const int qi = q0 + lq;

    for (int kt = 0; kt < 17; ++kt) {
        const int kbase = q0 - WINDOW_ + kt * 32;
        if (kbase + 32 <= 0) continue;                  // block-uniform

        // --- stage K tile [32 keys][256 d] ---
        {
            const int row = tid >> 3;
            const int co = (tid & 7) * 32;
            int kj = kbase + row;
            kj = min(max(kj, 0), L_ - 1);               // clamped rows are masked
            const short* src = kcol + (size_t)kj * QKVW + co;
            short* dst = &Ks[row][co];
#pragma unroll
            for (int u = 0; u < 4; ++u)
                *(int4*)(dst + u * 8) = *(const int4*)(src + u * 8);
        }
        // --- stage V^T tile [256 d][32 keys] ---
        {
            const short* src = vrow + (size_t)tid * L_;
#pragma unroll
            for (int c = 0; c < 4; ++c) {
                int ck = kbase + c * 8;
                ck = min(max(ck, 0), L_ - 8);
                *(int4*)&Vt[tid][c * 8] = *(const int4*)(src + ck);
            }
        }
        __syncthreads();

        // --- S^T = K Q^T : two 16-key subtiles ---
        f32x4 st0 = 0, st1 = 0;
#pragma unroll
        for (int f = 0; f < 8; ++f) {
            f16x8 kf0 = *(const f16x8*)&Ks[lq][f * 32 + quad * 8];
            f16x8 kf1 = *(const f16x8*)&Ks[16 + lq][f * 32 + quad * 8];
            st0 = __builtin_amdgcn_mfma_f32_16x16x32_f16(kf0, qf[f], st0, 0, 0, 0);
            st1 = __builtin_amdgcn_mfma_f32_16x16x32_f16(kf1, qf[f], st1, 0, 0, 0);
        }

        // --- register softmax (keys on (quad,r), query = lq) ---
        const int kA = kbase + quad * 4;        // keys for st0 regs
        const int kB = kA + 16;                 // keys for st1 regs
        float sv[8]; bool vd[8];
#pragma unroll
        for (int r = 0; r < 4; ++r) {
            int ka = kA + r, kb = kB + r;
            vd[r]     = (ka >= 0) && (ka <= qi) && (ka > qi - WINDOW_);
            vd[4 + r] = (kb >= 0) && (kb <= qi) && (kb > qi - WINDOW_);
            sv[r]     = vd[r]     ? st0[r] : -INFINITY;
            sv[4 + r] = vd[4 + r] ? st1[r] : -INFINITY;
        }
        float mt = sv[0];
#pragma unroll
        for (int i = 1; i < 8; ++i) mt = fmaxf(mt, sv[i]);
        mt = fmaxf(mt, __shfl_xor(mt, 16));
        mt = fmaxf(mt, __shfl_xor(mt, 32));
        const float mn = fmaxf(m_run, mt);
        const float alpha = (mn == -INFINITY) ? 1.0f : __expf(m_run - mn);
        float pv[8], rs = 0.0f;
#pragma unroll
        for (int i = 0; i < 8; ++i) {
            pv[i] = vd[i] ? __expf(sv[i] - mn) : 0.0f;
            rs += pv[i];
        }
        rs += __shfl_xor(rs, 16);
        rs += __shfl_xor(rs, 32);
        m_run = mn;
        l_run = l_run * alpha + rs;

        // P^T B-frags (B[k=quad*4+i][n=lq]) straight from registers
        f16x4 p0, p1;
#pragma unroll
        for (int i = 0; i < 4; ++i) { p0[i] = (_Float16)pv[i]; p1[i] = (_Float16)pv[4 + i]; }

        // --- PV: O^T[d][q] += V^T[d][k] P^T[k][q], 16x16x16 MFMAs ---
#pragma unroll
        for (int dt = 0; dt < 16; ++dt) {
            f16x4 v0 = *(const f16x4*)&Vt[dt * 16 + lq][quad * 4];
            f16x4 v1 = *(const f16x4*)&Vt[dt * 16 + lq][16 + quad * 4];
            f32x4 t = accO[dt];
#pragma unroll
            for (int r = 0; r < 4; ++r) t[r] *= alpha;
            t = __builtin_amdgcn_mfma_f32_16x16x16f16(v0, p0, t, 0, 0, 0);
            t = __builtin_amdgcn_mfma_f32_16x16x16f16(v1, p1, t, 0, 0, 0);
            accO[dt] = t;
        }
        __syncthreads();   // Ks/Vt consumed before next staging
    }

    // --- epilogue: untranspose O^T via per-wave LDS region, then coalesced store
    const float inv = 1.0f / l_run;            // per-query (lane) scalar
    short* myE = lds + w * 4224;               // 16 rows x 264 shorts per wave
#pragma unroll
    for (int dt = 0; dt < 16; ++dt) {
        f16x4 e;
#pragma unroll
        for (int r = 0; r < 4; ++r) e[r] = (_Float16)(accO[dt][r] * inv);
        *(f16x4*)&myE[lq * 264 + dt * 16 + quad * 4] = e;   // O[q=lq][d]
    }
    // same-wave read-back (lgkmcnt only), coalesced global store
    {
        const int row = lane >> 2;             // 16 q rows
        const int c0 = (lane & 3) * 64;        // 4 x 64-short segments
        short* orow = ao + (size_t)(q0 + row) * 2048 + h * HD_ + c0;
#pragma unroll
        for (int u = 0; u < 8; ++u)
            *(int4*)(orow + u * 8) = *(const int4*)&myE[row * 264 + c0 + u * 8];
    }
}

// ---------------------------------------------------------------------------
extern "C" void kernel_launch(void* const* d_in, const int* in_sizes, int n_in,
                              void* d_out, int out_size, void* d_ws, size_t ws_size,
                              hipStream_t stream) {
    const float* x         = (const float*)d_in[0];
    const int*   positions = (const int*)d_in[1];
    const float* Wq        = (const float*)d_in[2];
    const float* Wk        = (const float*)d_in[3];
    const float* Wv        = (const float*)d_in[4];
    const float* Wo        = (const float*)d_in[5];
    const float* q_scale   = (const float*)d_in[6];
    const float* k_scale   = (const float*)d_in[7];
    float*       out       = (float*)d_out;

    // workspace layout (bytes, ~80 MB total)
    char* ws = (char*)d_ws;
    short* xb    = (short*)(ws);                 // [4096][2048] f16   16 MB
    short* qkv   = (short*)(ws + 16777216);      // [4096][3072] f16   24 MB
    short* ao    = (short*)(ws + 41943040);      // [4096][2048] f16   16 MB
    short* Wtqkv = (short*)(ws + 58720256);      // [3072][2048] f16   12 MB
    short* Wto   = (short*)(ws + 71303168);      // [2048][2048] f16    8 MB
    short* vtg   = xb;                           // aliases xb (dead after QKV GEMM)

    // 1) casts + weight transposes
    cast_f16<<<4096, 256, 0, stream>>>(x, xb, L_ * D_);
    transpose_cast<<<dim3(2048 / 32, 2048 / 32), 256, 0, stream>>>(Wq, Wtqkv, D_, 2048);
    transpose_cast<<<dim3(512 / 32, 2048 / 32), 256, 0, stream>>>(Wk, Wtqkv + (size_t)2048 * D_, D_, 512);
    transpose_cast<<<dim3(512 / 32, 2048 / 32), 256, 0, stream>>>(Wv, Wtqkv + (size_t)2560 * D_, D_, 512);
    transpose_cast<<<dim3(2048 / 32, 2048 / 32), 256, 0, stream>>>(Wo, Wto, 2048, 2048);

    // 2) fused QKV projection (f16 out)
    gemm_mfma<1><<<dim3(QKVW / 128, L_ / 128), 256, 0, stream>>>(xb, Wtqkv, qkv, L_, QKVW, D_);

    // 3) RMSNorm + RoPE in place
    norm_rope_h<<<L_ * 12, 256, 0, stream>>>(qkv, q_scale, k_scale, positions);

    // 4) V transpose to [g][d][L] (into xb region, now dead)
    vt_prep<<<dim3(L_ / 64, KVH_), 256, 0, stream>>>(qkv, vtg);

    // 5) flash MFMA attention v3
    attn_mfma<<<(L_ / 16) * KVH_, 256, 0, stream>>>(qkv, vtg, ao);

    // 6) output projection (fp32 out)
    gemm_mfma<0><<<dim3(D_ / 128, L_ / 128), 256, 0, stream>>>(ao, Wto, out, L_, D_, 2048);
}